// Round 4
// baseline (334.553 us; speedup 1.0000x reference)
//
#include <hip/hip_runtime.h>
#include <hip/hip_bf16.h>

typedef __hip_bfloat16 bf16;
typedef __bf16 v8bf __attribute__((ext_vector_type(8)));
typedef float  v4f  __attribute__((ext_vector_type(4)));

struct __align__(8) bf16x4 { bf16 x, y, z, w; };

__device__ __forceinline__ bf16 f2b(float v) { return __float2bfloat16(v); }

// B=8, C=512, H=W=64 -> N=4096, HEADS=4, d=128, GROUPS=32
#define NSP 4096
#define CCH 512

// Async 16B global -> LDS (gfx950 direct-to-LDS, wave-uniform base + lane*16).
__device__ __forceinline__ void async_cp16(const bf16* g, __bf16* l) {
    __builtin_amdgcn_global_load_lds(
        (const __attribute__((address_space(1))) unsigned int*)(unsigned long long)g,
        (__attribute__((address_space(3))) unsigned int*)(unsigned int)(unsigned long long)l,
        16, 0, 0);
}

// ---------------------------------------------------------------------------
// Weight fp32 -> bf16 conversion (runs every launch; weights are re-restored).
// ---------------------------------------------------------------------------
__global__ __launch_bounds__(256) void wconv_kernel(const float* __restrict__ src,
                                                    bf16* __restrict__ dst, int n4) {
    int i = blockIdx.x * 256 + threadIdx.x;
    if (i < n4) {
        float4 v = ((const float4*)src)[i];
        bf16x4 o = { f2b(v.x), f2b(v.y), f2b(v.z), f2b(v.w) };
        ((bf16x4*)dst)[i] = o;
    }
}

// ---------------------------------------------------------------------------
// GN pass 1: per-(b,group) mean/rstd. 256 blocks.
// ---------------------------------------------------------------------------
__global__ __launch_bounds__(256) void gn_stats_kernel(const float* __restrict__ x,
                                                       float* __restrict__ stats) {
    int blk = blockIdx.x;
    int b = blk >> 5, g = blk & 31;
    size_t base = ((size_t)(b * CCH + g * 16)) * NSP;     // 65536 floats
    const float4* xp4 = (const float4*)(x + base);
    int t = threadIdx.x;
    float s = 0.f, s2 = 0.f;
    for (int i = t; i < 16384; i += 256) {
        float4 v = xp4[i];
        s  += v.x + v.y + v.z + v.w;
        s2 += v.x * v.x + v.y * v.y + v.z * v.z + v.w * v.w;
    }
    for (int off = 32; off > 0; off >>= 1) {
        s  += __shfl_down(s, off);
        s2 += __shfl_down(s2, off);
    }
    __shared__ float red[8];
    int wid = t >> 6, lid = t & 63;
    if (lid == 0) { red[wid] = s; red[wid + 4] = s2; }
    __syncthreads();
    if (t == 0) {
        float ts  = red[0] + red[1] + red[2] + red[3];
        float ts2 = red[4] + red[5] + red[6] + red[7];
        float mean = ts * (1.f / 65536.f);
        float var  = ts2 * (1.f / 65536.f) - mean * mean;
        stats[blk * 2]     = mean;
        stats[blk * 2 + 1] = rsqrtf(var + 1e-5f);
    }
}

// ---------------------------------------------------------------------------
// GN pass 2: normalize + transpose to n-major hnT[b][n][c] (bf16).
// ---------------------------------------------------------------------------
__global__ __launch_bounds__(256) void gn_norm_t_kernel(const float* __restrict__ x,
                                                        const float* __restrict__ gw,
                                                        const float* __restrict__ gb,
                                                        const float* __restrict__ stats,
                                                        bf16* __restrict__ hnT) {
    __shared__ float sT[64][65];
    int n0 = blockIdx.x * 64, c0 = blockIdx.y * 64, b = blockIdx.z;
    int t = threadIdx.x;
    int cl = t >> 4, nl4 = (t & 15) << 2;
#pragma unroll
    for (int it = 0; it < 4; ++it) {
        int crow = cl + it * 16;
        int c = c0 + crow;
        int bg = b * 32 + (c >> 4);
        float mean = stats[bg * 2], rstd = stats[bg * 2 + 1];
        float wsc = gw[c] * rstd;
        float bb  = gb[c] - mean * wsc;
        float4 v = *(const float4*)&x[((long)b * CCH + c) * NSP + n0 + nl4];
        sT[crow][nl4 + 0] = v.x * wsc + bb;
        sT[crow][nl4 + 1] = v.y * wsc + bb;
        sT[crow][nl4 + 2] = v.z * wsc + bb;
        sT[crow][nl4 + 3] = v.w * wsc + bb;
    }
    __syncthreads();
    int nl = t >> 4, cl4 = (t & 15) << 2;
#pragma unroll
    for (int it = 0; it < 4; ++it) {
        int nrow = nl + it * 16;
        bf16x4 ov = { f2b(sT[cl4 + 0][nrow]), f2b(sT[cl4 + 1][nrow]),
                      f2b(sT[cl4 + 2][nrow]), f2b(sT[cl4 + 3][nrow]) };
        *(bf16x4*)&hnT[((long)b * NSP + n0 + nrow) * CCH + c0 + cl4] = ov;
    }
}

// ---------------------------------------------------------------------------
// MFMA GEMM core: 128x128 tile, BK=64, 256 threads (4 waves 2x2).
// A/B tiles [128 rows][64 k], k contiguous in source, both bf16.
// Staging: 4+4 async 16B global_load_lds issues/thread per K-step,
// linear LDS layout (wave-uniform base + lane*16).
// 32 MFMA per barrier pair (AITER-class amortization).
// acc[i][j]: wave subtile (i=row, j=col) 16x16; acc may be pre-initialized
// (bias / residual) by the caller.
// ---------------------------------------------------------------------------
__device__ __forceinline__ void gemm_core(const bf16* __restrict__ A, long as,
                                          const bf16* __restrict__ B, long bs,
                                          int K, v4f acc[4][4],
                                          __bf16* sA, __bf16* sB) {
    int t = threadIdx.x;
    int lane = t & 63, wv = t >> 6;
    int wr = wv >> 1, wc = wv & 1;
    int lq = lane & 15, quad = lane >> 4;
    const __bf16* aBase = sA + (wr * 64) * 64;
    const __bf16* bBase = sB + (wc * 64) * 64;

    for (int k0 = 0; k0 < K; k0 += 64) {
        __syncthreads();                 // prior-iteration LDS reads done
#pragma unroll
        for (int i = 0; i < 4; ++i) {
            int idx = i * 256 + t;
            int row = idx >> 3;          // 8 chunks of 16B per 64-elem row
            int ko  = (idx & 7) * 8;
            async_cp16(A + (long)row * as + k0 + ko, sA + idx * 8);
            async_cp16(B + (long)row * bs + k0 + ko, sB + idx * 8);
        }
        __syncthreads();                 // vmcnt drained at barrier -> visible
#pragma unroll
        for (int kk = 0; kk < 2; ++kk) {
            v8bf a[4], bfr[4];
#pragma unroll
            for (int i = 0; i < 4; ++i)
                a[i] = *(const v8bf*)(aBase + (i * 16 + lq) * 64 + kk * 32 + quad * 8);
#pragma unroll
            for (int j = 0; j < 4; ++j)
                bfr[j] = *(const v8bf*)(bBase + (j * 16 + lq) * 64 + kk * 32 + quad * 8);
#pragma unroll
            for (int i = 0; i < 4; ++i)
#pragma unroll
                for (int j = 0; j < 4; ++j)
                    acc[i][j] = __builtin_amdgcn_mfma_f32_16x16x32_bf16(a[i], bfr[j], acc[i][j], 0, 0, 0);
        }
    }
}

// ---------------------------------------------------------------------------
// QKV GEMM (swapped): D[n][o] = sum_k hnT[n][k] * Wqkv[o][k]  (+bias)
// q,k (o<1024) -> qkbuf[b][o][n]; v (o>=1024) -> vT[b][n][e].
// grid (32 n-tiles, 12 o-tiles, 8 b)
// ---------------------------------------------------------------------------
__global__ __launch_bounds__(256) void qkv_gemm_kernel(const bf16* __restrict__ hnT,
                                                       const bf16* __restrict__ qkv_wb,
                                                       const float* __restrict__ qkv_b,
                                                       bf16* __restrict__ qkbuf,
                                                       bf16* __restrict__ vT) {
    __shared__ __align__(16) __bf16 sA[128 * 64];
    __shared__ __align__(16) __bf16 sB[128 * 64];
    int n0 = blockIdx.x * 128, o0 = blockIdx.y * 128, b = blockIdx.z;
    int t = threadIdx.x, lane = t & 63, wv = t >> 6, wr = wv >> 1, wc = wv & 1;
    int lq = lane & 15, quad = lane >> 4;
    v4f acc[4][4];
#pragma unroll
    for (int j = 0; j < 4; ++j) {
        float bias = qkv_b[o0 + wc * 64 + j * 16 + lq];
#pragma unroll
        for (int i = 0; i < 4; ++i) acc[i][j] = { bias, bias, bias, bias };
    }
    gemm_core(hnT + ((long)b * NSP + n0) * CCH, CCH,
              qkv_wb + (long)o0 * CCH, CCH, CCH, acc, sA, sB);
#pragma unroll
    for (int j = 0; j < 4; ++j) {
        int o = o0 + wc * 64 + j * 16 + lq;
#pragma unroll
        for (int i = 0; i < 4; ++i) {
            int n = n0 + wr * 64 + i * 16 + quad * 4;
            v4f v = acc[i][j];
            if (o0 < 1024) {
                bf16x4 ov = { f2b(v[0]), f2b(v[1]), f2b(v[2]), f2b(v[3]) };
                *(bf16x4*)&qkbuf[((long)b * 1024 + o) * NSP + n] = ov;
            } else {
#pragma unroll
                for (int r = 0; r < 4; ++r)
                    vT[((long)b * NSP + n + r) * CCH + (o - 1024)] = f2b(v[r]);
            }
        }
    }
}

// ---------------------------------------------------------------------------
// QK^T split-K: P_part[s][bh][d][e] = sum_{n in split} q[d][n]*k[e][n]
// grid (8 splits, 32 bh)
// ---------------------------------------------------------------------------
__global__ __launch_bounds__(256) void qk_gemm_kernel(const bf16* __restrict__ qkbuf,
                                                      float* __restrict__ P_part) {
    __shared__ __align__(16) __bf16 sA[128 * 64];
    __shared__ __align__(16) __bf16 sB[128 * 64];
    int s = blockIdx.x, bh = blockIdx.y;
    int b = bh >> 2, h = bh & 3;
    const bf16* q  = qkbuf + ((long)b * 1024 + h * 128) * NSP + s * 512;
    const bf16* kk = qkbuf + ((long)b * 1024 + 512 + h * 128) * NSP + s * 512;
    v4f acc[4][4] = {};
    gemm_core(q, NSP, kk, NSP, 512, acc, sA, sB);
    float* Pp = P_part + ((long)s * 32 + bh) * 16384;
    int t = threadIdx.x, lane = t & 63, wv = t >> 6, wr = wv >> 1, wc = wv & 1;
    int lq = lane & 15, quad = lane >> 4;
#pragma unroll
    for (int j = 0; j < 4; ++j) {
        int e = wc * 64 + j * 16 + lq;
#pragma unroll
        for (int i = 0; i < 4; ++i) {
            int d = wr * 64 + i * 16 + quad * 4;
            v4f v = acc[i][j];
#pragma unroll
            for (int r = 0; r < 4; ++r) Pp[(long)(d + r) * 128 + e] = v[r];
        }
    }
}

// ---------------------------------------------------------------------------
// Softmax: sum 8 partials, scale by d^-0.5, softmax over e, emit bf16 P.
// ---------------------------------------------------------------------------
__global__ __launch_bounds__(128) void softmax_kernel(const float* __restrict__ P_part,
                                                      bf16* __restrict__ Pb) {
    int row = blockIdx.x;
    int bh = row >> 7, d = row & 127;
    int t = threadIdx.x;
    float v = 0.f;
#pragma unroll
    for (int s = 0; s < 8; ++s)
        v += P_part[((long)s * 32 + bh) * 16384 + (long)d * 128 + t];
    v *= 0.08838834764831845f;
    float m = v;
    for (int off = 32; off > 0; off >>= 1) m = fmaxf(m, __shfl_down(m, off));
    __shared__ float sm[2];
    if ((t & 63) == 0) sm[t >> 6] = m;
    __syncthreads();
    m = fmaxf(sm[0], sm[1]);
    float e = __expf(v - m);
    float ssum = e;
    for (int off = 32; off > 0; off >>= 1) ssum += __shfl_down(ssum, off);
    __shared__ float ss[2];
    if ((t & 63) == 0) ss[t >> 6] = ssum;
    __syncthreads();
    ssum = ss[0] + ss[1];
    Pb[(long)row * 128 + t] = f2b(e / ssum);
}

// ---------------------------------------------------------------------------
// PV: attT[b][n][h*128+d] = sum_e P[d][e] * vT[n][e].  grid (32 n-tiles, 32 bh)
// ---------------------------------------------------------------------------
__global__ __launch_bounds__(256) void pv_gemm_kernel(const bf16* __restrict__ Pb,
                                                      const bf16* __restrict__ vT,
                                                      bf16* __restrict__ attT) {
    __shared__ __align__(16) __bf16 sA[128 * 64];
    __shared__ __align__(16) __bf16 sB[128 * 64];
    int n0 = blockIdx.x * 128, bh = blockIdx.y;
    int b = bh >> 2, h = bh & 3;
    v4f acc[4][4] = {};
    gemm_core(Pb + (long)bh * 16384, 128,
              vT + ((long)b * NSP + n0) * CCH + h * 128, CCH, 128, acc, sA, sB);
    int t = threadIdx.x, lane = t & 63, wv = t >> 6, wr = wv >> 1, wc = wv & 1;
    int lq = lane & 15, quad = lane >> 4;
#pragma unroll
    for (int j = 0; j < 4; ++j) {
        int n = n0 + wc * 64 + j * 16 + lq;
#pragma unroll
        for (int i = 0; i < 4; ++i) {
            int d = wr * 64 + i * 16 + quad * 4;
            v4f v = acc[i][j];
            bf16x4 ov = { f2b(v[0]), f2b(v[1]), f2b(v[2]), f2b(v[3]) };
            *(bf16x4*)&attT[((long)b * NSP + n) * CCH + h * 128 + d] = ov;
        }
    }
}

// ---------------------------------------------------------------------------
// Proj (swapped): out[b][c][n] = sum_k attT[n][k]*Wp[c][k] + bias[c] + x
// Residual + bias are folded into the accumulator init so the x-read
// overlaps the K-loop; epilogue is pure stores.
// grid (32 n-tiles, 4 c-tiles, 8 b)
// ---------------------------------------------------------------------------
__global__ __launch_bounds__(256) void proj_gemm_kernel(const bf16* __restrict__ attT,
                                                        const bf16* __restrict__ proj_wb,
                                                        const float* __restrict__ proj_b,
                                                        const float* __restrict__ x,
                                                        float* __restrict__ out) {
    __shared__ __align__(16) __bf16 sA[128 * 64];
    __shared__ __align__(16) __bf16 sB[128 * 64];
    int n0 = blockIdx.x * 128, c0 = blockIdx.y * 128, b = blockIdx.z;
    int t = threadIdx.x, lane = t & 63, wv = t >> 6, wr = wv >> 1, wc = wv & 1;
    int lq = lane & 15, quad = lane >> 4;
    v4f acc[4][4];
#pragma unroll
    for (int j = 0; j < 4; ++j) {
        int c = c0 + wc * 64 + j * 16 + lq;
        float bias = proj_b[c];
#pragma unroll
        for (int i = 0; i < 4; ++i) {
            int n = n0 + wr * 64 + i * 16 + quad * 4;
            float4 r = *(const float4*)&x[((long)b * CCH + c) * NSP + n];
            acc[i][j] = { r.x + bias, r.y + bias, r.z + bias, r.w + bias };
        }
    }
    gemm_core(attT + ((long)b * NSP + n0) * CCH, CCH,
              proj_wb + (long)c0 * CCH, CCH, CCH, acc, sA, sB);
#pragma unroll
    for (int j = 0; j < 4; ++j) {
        int c = c0 + wc * 64 + j * 16 + lq;
#pragma unroll
        for (int i = 0; i < 4; ++i) {
            int n = n0 + wr * 64 + i * 16 + quad * 4;
            long idx = ((long)b * CCH + c) * NSP + n;
            v4f v = acc[i][j];
            float4 ov = { v[0], v[1], v[2], v[3] };
            *(float4*)&out[idx] = ov;
        }
    }
}

// ---------------------------------------------------------------------------
extern "C" void kernel_launch(void* const* d_in, const int* in_sizes, int n_in,
                              void* d_out, int out_size, void* d_ws, size_t ws_size,
                              hipStream_t stream) {
    const float* x      = (const float*)d_in[0];
    const float* gn_w   = (const float*)d_in[1];
    const float* gn_b   = (const float*)d_in[2];
    const float* qkv_w  = (const float*)d_in[3];
    const float* qkv_b  = (const float*)d_in[4];
    const float* proj_w = (const float*)d_in[5];
    const float* proj_b = (const float*)d_in[6];
    float* out = (float*)d_out;

    char* ws = (char*)d_ws;
    // region0 (33.5 MB) reused over time: hnT -> P_part -> attT
    bf16*  hnT    = (bf16*)ws;
    float* P_part = (float*)ws;                    // 8*32*128*128 fp32 = 16.8 MB
    bf16*  attT   = (bf16*)ws;
    bf16*  qkbuf  = (bf16*)(ws + 33554432);        // [b][1024][4096] bf16 = 67.1 MB
    bf16*  vT     = (bf16*)(ws + 100663296);       // [b][4096][512]  bf16 = 33.5 MB
    bf16*  Pb     = (bf16*)(ws + 134217728);       // 32*128*128 bf16 = 1 MB
    float* stats  = (float*)(ws + 135266304);      // 256*2 fp32
    bf16*  qkv_wb = (bf16*)(ws + 135270400);       // 1536*512 bf16 = 1.5 MB
    bf16*  proj_wb= (bf16*)(ws + 136843264);       // 512*512 bf16 = 0.5 MB

    wconv_kernel<<<768, 256, 0, stream>>>(qkv_w, qkv_wb, 196608);
    wconv_kernel<<<256, 256, 0, stream>>>(proj_w, proj_wb, 65536);
    gn_stats_kernel<<<256, 256, 0, stream>>>(x, stats);
    gn_norm_t_kernel<<<dim3(64, 8, 8), 256, 0, stream>>>(x, gn_w, gn_b, stats, hnT);
    qkv_gemm_kernel<<<dim3(32, 12, 8), 256, 0, stream>>>(hnT, qkv_wb, qkv_b, qkbuf, vT);
    qk_gemm_kernel<<<dim3(8, 32), 256, 0, stream>>>(qkbuf, P_part);
    softmax_kernel<<<4096, 128, 0, stream>>>(P_part, Pb);
    pv_gemm_kernel<<<dim3(32, 32), 256, 0, stream>>>(Pb, vT, attT);
    proj_gemm_kernel<<<dim3(32, 4, 8), 256, 0, stream>>>(attT, proj_wb, proj_b, x, out);
}

// Round 5
// 330.825 us; speedup vs baseline: 1.0113x; 1.0113x over previous
//
#include <hip/hip_runtime.h>
#include <hip/hip_bf16.h>

typedef __hip_bfloat16 bf16;
typedef __bf16 v8bf __attribute__((ext_vector_type(8)));
typedef float  v4f  __attribute__((ext_vector_type(4)));

struct __align__(8) bf16x4 { bf16 x, y, z, w; };

__device__ __forceinline__ bf16 f2b(float v) { return __float2bfloat16(v); }

// B=8, C=512, H=W=64 -> N=4096, HEADS=4, d=128, GROUPS=32
#define NSP 4096
#define CCH 512

// Async 16B global -> LDS (gfx950 direct-to-LDS, wave-uniform base + lane*16).
__device__ __forceinline__ void async_cp16(const bf16* g, __bf16* l) {
    __builtin_amdgcn_global_load_lds(
        (const __attribute__((address_space(1))) unsigned int*)(unsigned long long)g,
        (__attribute__((address_space(3))) unsigned int*)(unsigned int)(unsigned long long)l,
        16, 0, 0);
}

// ---------------------------------------------------------------------------
// Weight fp32 -> bf16 conversion (runs every launch; weights are re-restored).
// ---------------------------------------------------------------------------
__global__ __launch_bounds__(256) void wconv_kernel(const float* __restrict__ src,
                                                    bf16* __restrict__ dst, int n4) {
    int i = blockIdx.x * 256 + threadIdx.x;
    if (i < n4) {
        float4 v = ((const float4*)src)[i];
        bf16x4 o = { f2b(v.x), f2b(v.y), f2b(v.z), f2b(v.w) };
        ((bf16x4*)dst)[i] = o;
    }
}

// ---------------------------------------------------------------------------
// GN pass 1: per-(b,group) mean/rstd. 256 blocks.
// ---------------------------------------------------------------------------
__global__ __launch_bounds__(256) void gn_stats_kernel(const float* __restrict__ x,
                                                       float* __restrict__ stats) {
    int blk = blockIdx.x;
    int b = blk >> 5, g = blk & 31;
    size_t base = ((size_t)(b * CCH + g * 16)) * NSP;     // 65536 floats
    const float4* xp4 = (const float4*)(x + base);
    int t = threadIdx.x;
    float s = 0.f, s2 = 0.f;
    for (int i = t; i < 16384; i += 256) {
        float4 v = xp4[i];
        s  += v.x + v.y + v.z + v.w;
        s2 += v.x * v.x + v.y * v.y + v.z * v.z + v.w * v.w;
    }
    for (int off = 32; off > 0; off >>= 1) {
        s  += __shfl_down(s, off);
        s2 += __shfl_down(s2, off);
    }
    __shared__ float red[8];
    int wid = t >> 6, lid = t & 63;
    if (lid == 0) { red[wid] = s; red[wid + 4] = s2; }
    __syncthreads();
    if (t == 0) {
        float ts  = red[0] + red[1] + red[2] + red[3];
        float ts2 = red[4] + red[5] + red[6] + red[7];
        float mean = ts * (1.f / 65536.f);
        float var  = ts2 * (1.f / 65536.f) - mean * mean;
        stats[blk * 2]     = mean;
        stats[blk * 2 + 1] = rsqrtf(var + 1e-5f);
    }
}

// ---------------------------------------------------------------------------
// GN pass 2: normalize + transpose to n-major hnT[b][n][c] (bf16).
// ---------------------------------------------------------------------------
__global__ __launch_bounds__(256) void gn_norm_t_kernel(const float* __restrict__ x,
                                                        const float* __restrict__ gw,
                                                        const float* __restrict__ gb,
                                                        const float* __restrict__ stats,
                                                        bf16* __restrict__ hnT) {
    __shared__ float sT[64][65];
    int n0 = blockIdx.x * 64, c0 = blockIdx.y * 64, b = blockIdx.z;
    int t = threadIdx.x;
    int cl = t >> 4, nl4 = (t & 15) << 2;
#pragma unroll
    for (int it = 0; it < 4; ++it) {
        int crow = cl + it * 16;
        int c = c0 + crow;
        int bg = b * 32 + (c >> 4);
        float mean = stats[bg * 2], rstd = stats[bg * 2 + 1];
        float wsc = gw[c] * rstd;
        float bb  = gb[c] - mean * wsc;
        float4 v = *(const float4*)&x[((long)b * CCH + c) * NSP + n0 + nl4];
        sT[crow][nl4 + 0] = v.x * wsc + bb;
        sT[crow][nl4 + 1] = v.y * wsc + bb;
        sT[crow][nl4 + 2] = v.z * wsc + bb;
        sT[crow][nl4 + 3] = v.w * wsc + bb;
    }
    __syncthreads();
    int nl = t >> 4, cl4 = (t & 15) << 2;
#pragma unroll
    for (int it = 0; it < 4; ++it) {
        int nrow = nl + it * 16;
        bf16x4 ov = { f2b(sT[cl4 + 0][nrow]), f2b(sT[cl4 + 1][nrow]),
                      f2b(sT[cl4 + 2][nrow]), f2b(sT[cl4 + 3][nrow]) };
        *(bf16x4*)&hnT[((long)b * NSP + n0 + nrow) * CCH + c0 + cl4] = ov;
    }
}

// ---------------------------------------------------------------------------
// MFMA GEMM core: 128x128 tile, BK=32, 256 threads (4 waves 2x2).
// A/B tiles [128 rows][32 k], k contiguous in source, both bf16.
// Staging via global_load_lds dwordx4 (wave-uniform base + lane*16).
//
// Bank-conflict swizzle: the tile is stored as 512 chunks of 16B. Logical
// chunk (row, c) [c = 0..3 within the 64B row] lives at physical slot
// p = row*4 + ((c + (row>>1)) & 3). Staging inverts this when computing the
// *global* source address (per-wave address set unchanged -> coalescing
// unchanged); reads add a lane-uniform swizzle term. Result: 8 consecutive
// lanes of a ds_read_b128 start at banks {0,16,4,20,8,24,12,28} ->
// conflict-free.
// ---------------------------------------------------------------------------
__device__ __forceinline__ void gemm_core(const bf16* __restrict__ A, long as,
                                          const bf16* __restrict__ B, long bs,
                                          int K, v4f acc[4][4],
                                          __bf16* sA, __bf16* sB) {
    int t = threadIdx.x;
    int lane = t & 63, wv = t >> 6;
    int wr = wv >> 1, wc = wv & 1;
    int lq = lane & 15, quad = lane >> 4;
    // staging: thread t owns physical chunks p0 = t, p1 = t + 256
    int p0 = t, p1 = t + 256;
    int r0 = p0 >> 2, c0 = ((p0 & 3) - ((p0 >> 3) & 3)) & 3;
    int r1 = p1 >> 2, c1 = ((p1 & 3) - ((p1 >> 3) & 3)) & 3;
    __bf16* lA0 = sA + p0 * 8;
    __bf16* lA1 = sA + p1 * 8;
    __bf16* lB0 = sB + p0 * 8;
    __bf16* lB1 = sB + p1 * 8;
    // read swizzle (independent of fragment index i/j)
    int ssw = (quad + ((lq >> 1) & 3)) & 3;
    const __bf16* aBase = sA + (wr * 64) * 32 + ssw * 8;
    const __bf16* bBase = sB + (wc * 64) * 32 + ssw * 8;

    for (int k0 = 0; k0 < K; k0 += 32) {
        __syncthreads();                 // prior-iteration LDS reads done
        async_cp16(A + (long)r0 * as + k0 + c0 * 8, lA0);
        async_cp16(A + (long)r1 * as + k0 + c1 * 8, lA1);
        async_cp16(B + (long)r0 * bs + k0 + c0 * 8, lB0);
        async_cp16(B + (long)r1 * bs + k0 + c1 * 8, lB1);
        __syncthreads();                 // vmcnt drained at barrier -> visible
        v8bf a[4], bfr[4];
#pragma unroll
        for (int i = 0; i < 4; ++i)
            a[i] = *(const v8bf*)(aBase + (i * 16 + lq) * 32);
#pragma unroll
        for (int j = 0; j < 4; ++j)
            bfr[j] = *(const v8bf*)(bBase + (j * 16 + lq) * 32);
#pragma unroll
        for (int i = 0; i < 4; ++i)
#pragma unroll
            for (int j = 0; j < 4; ++j)
                acc[i][j] = __builtin_amdgcn_mfma_f32_16x16x32_bf16(a[i], bfr[j], acc[i][j], 0, 0, 0);
    }
}

// ---------------------------------------------------------------------------
// QKV GEMM (swapped): D[n][o] = sum_k hnT[n][k] * Wqkv[o][k]  (+bias)
// q,k (o<1024) -> qkbuf[b][o][n]; v (o>=1024) -> vT[b][n][e].
// grid (32 n-tiles, 12 o-tiles, 8 b)
// ---------------------------------------------------------------------------
__global__ __launch_bounds__(256) void qkv_gemm_kernel(const bf16* __restrict__ hnT,
                                                       const bf16* __restrict__ qkv_wb,
                                                       const float* __restrict__ qkv_b,
                                                       bf16* __restrict__ qkbuf,
                                                       bf16* __restrict__ vT) {
    __shared__ __align__(16) __bf16 sA[128 * 32];
    __shared__ __align__(16) __bf16 sB[128 * 32];
    int n0 = blockIdx.x * 128, o0 = blockIdx.y * 128, b = blockIdx.z;
    int t = threadIdx.x, lane = t & 63, wv = t >> 6, wr = wv >> 1, wc = wv & 1;
    int lq = lane & 15, quad = lane >> 4;
    v4f acc[4][4];
#pragma unroll
    for (int j = 0; j < 4; ++j) {
        float bias = qkv_b[o0 + wc * 64 + j * 16 + lq];
#pragma unroll
        for (int i = 0; i < 4; ++i) acc[i][j] = { bias, bias, bias, bias };
    }
    gemm_core(hnT + ((long)b * NSP + n0) * CCH, CCH,
              qkv_wb + (long)o0 * CCH, CCH, CCH, acc, sA, sB);
#pragma unroll
    for (int j = 0; j < 4; ++j) {
        int o = o0 + wc * 64 + j * 16 + lq;
#pragma unroll
        for (int i = 0; i < 4; ++i) {
            int n = n0 + wr * 64 + i * 16 + quad * 4;
            v4f v = acc[i][j];
            if (o0 < 1024) {
                bf16x4 ov = { f2b(v[0]), f2b(v[1]), f2b(v[2]), f2b(v[3]) };
                *(bf16x4*)&qkbuf[((long)b * 1024 + o) * NSP + n] = ov;
            } else {
#pragma unroll
                for (int r = 0; r < 4; ++r)
                    vT[((long)b * NSP + n + r) * CCH + (o - 1024)] = f2b(v[r]);
            }
        }
    }
}

// ---------------------------------------------------------------------------
// QK^T split-K: P_part[s][bh][d][e] = sum_{n in split} q[d][n]*k[e][n]
// grid (8 splits, 32 bh)
// ---------------------------------------------------------------------------
__global__ __launch_bounds__(256) void qk_gemm_kernel(const bf16* __restrict__ qkbuf,
                                                      float* __restrict__ P_part) {
    __shared__ __align__(16) __bf16 sA[128 * 32];
    __shared__ __align__(16) __bf16 sB[128 * 32];
    int s = blockIdx.x, bh = blockIdx.y;
    int b = bh >> 2, h = bh & 3;
    const bf16* q  = qkbuf + ((long)b * 1024 + h * 128) * NSP + s * 512;
    const bf16* kk = qkbuf + ((long)b * 1024 + 512 + h * 128) * NSP + s * 512;
    v4f acc[4][4] = {};
    gemm_core(q, NSP, kk, NSP, 512, acc, sA, sB);
    float* Pp = P_part + ((long)s * 32 + bh) * 16384;
    int t = threadIdx.x, lane = t & 63, wv = t >> 6, wr = wv >> 1, wc = wv & 1;
    int lq = lane & 15, quad = lane >> 4;
#pragma unroll
    for (int j = 0; j < 4; ++j) {
        int e = wc * 64 + j * 16 + lq;
#pragma unroll
        for (int i = 0; i < 4; ++i) {
            int d = wr * 64 + i * 16 + quad * 4;
            v4f v = acc[i][j];
#pragma unroll
            for (int r = 0; r < 4; ++r) Pp[(long)(d + r) * 128 + e] = v[r];
        }
    }
}

// ---------------------------------------------------------------------------
// Softmax: sum 8 partials, scale by d^-0.5, softmax over e, emit bf16 P.
// ---------------------------------------------------------------------------
__global__ __launch_bounds__(128) void softmax_kernel(const float* __restrict__ P_part,
                                                      bf16* __restrict__ Pb) {
    int row = blockIdx.x;
    int bh = row >> 7, d = row & 127;
    int t = threadIdx.x;
    float v = 0.f;
#pragma unroll
    for (int s = 0; s < 8; ++s)
        v += P_part[((long)s * 32 + bh) * 16384 + (long)d * 128 + t];
    v *= 0.08838834764831845f;
    float m = v;
    for (int off = 32; off > 0; off >>= 1) m = fmaxf(m, __shfl_down(m, off));
    __shared__ float sm[2];
    if ((t & 63) == 0) sm[t >> 6] = m;
    __syncthreads();
    m = fmaxf(sm[0], sm[1]);
    float e = __expf(v - m);
    float ssum = e;
    for (int off = 32; off > 0; off >>= 1) ssum += __shfl_down(ssum, off);
    __shared__ float ss[2];
    if ((t & 63) == 0) ss[t >> 6] = ssum;
    __syncthreads();
    ssum = ss[0] + ss[1];
    Pb[(long)row * 128 + t] = f2b(e / ssum);
}

// ---------------------------------------------------------------------------
// PV: attT[b][n][h*128+d] = sum_e P[d][e] * vT[n][e].  grid (32 n-tiles, 32 bh)
// ---------------------------------------------------------------------------
__global__ __launch_bounds__(256) void pv_gemm_kernel(const bf16* __restrict__ Pb,
                                                      const bf16* __restrict__ vT,
                                                      bf16* __restrict__ attT) {
    __shared__ __align__(16) __bf16 sA[128 * 32];
    __shared__ __align__(16) __bf16 sB[128 * 32];
    int n0 = blockIdx.x * 128, bh = blockIdx.y;
    int b = bh >> 2, h = bh & 3;
    v4f acc[4][4] = {};
    gemm_core(Pb + (long)bh * 16384, 128,
              vT + ((long)b * NSP + n0) * CCH + h * 128, CCH, 128, acc, sA, sB);
    int t = threadIdx.x, lane = t & 63, wv = t >> 6, wr = wv >> 1, wc = wv & 1;
    int lq = lane & 15, quad = lane >> 4;
#pragma unroll
    for (int j = 0; j < 4; ++j) {
        int n = n0 + wc * 64 + j * 16 + lq;
#pragma unroll
        for (int i = 0; i < 4; ++i) {
            int d = wr * 64 + i * 16 + quad * 4;
            v4f v = acc[i][j];
            bf16x4 ov = { f2b(v[0]), f2b(v[1]), f2b(v[2]), f2b(v[3]) };
            *(bf16x4*)&attT[((long)b * NSP + n) * CCH + h * 128 + d] = ov;
        }
    }
}

// ---------------------------------------------------------------------------
// Proj (swapped): out[b][c][n] = sum_k attT[n][k]*Wp[c][k] + bias[c] + x
// Residual + bias folded into accumulator init (x-read overlaps K-loop).
// grid (32 n-tiles, 4 c-tiles, 8 b)
// ---------------------------------------------------------------------------
__global__ __launch_bounds__(256) void proj_gemm_kernel(const bf16* __restrict__ attT,
                                                        const bf16* __restrict__ proj_wb,
                                                        const float* __restrict__ proj_b,
                                                        const float* __restrict__ x,
                                                        float* __restrict__ out) {
    __shared__ __align__(16) __bf16 sA[128 * 32];
    __shared__ __align__(16) __bf16 sB[128 * 32];
    int n0 = blockIdx.x * 128, c0 = blockIdx.y * 128, b = blockIdx.z;
    int t = threadIdx.x, lane = t & 63, wv = t >> 6, wr = wv >> 1, wc = wv & 1;
    int lq = lane & 15, quad = lane >> 4;
    v4f acc[4][4];
#pragma unroll
    for (int j = 0; j < 4; ++j) {
        int c = c0 + wc * 64 + j * 16 + lq;
        float bias = proj_b[c];
#pragma unroll
        for (int i = 0; i < 4; ++i) {
            int n = n0 + wr * 64 + i * 16 + quad * 4;
            float4 r = *(const float4*)&x[((long)b * CCH + c) * NSP + n];
            acc[i][j] = { r.x + bias, r.y + bias, r.z + bias, r.w + bias };
        }
    }
    gemm_core(attT + ((long)b * NSP + n0) * CCH, CCH,
              proj_wb + (long)c0 * CCH, CCH, CCH, acc, sA, sB);
#pragma unroll
    for (int j = 0; j < 4; ++j) {
        int c = c0 + wc * 64 + j * 16 + lq;
#pragma unroll
        for (int i = 0; i < 4; ++i) {
            int n = n0 + wr * 64 + i * 16 + quad * 4;
            long idx = ((long)b * CCH + c) * NSP + n;
            v4f v = acc[i][j];
            float4 ov = { v[0], v[1], v[2], v[3] };
            *(float4*)&out[idx] = ov;
        }
    }
}

// ---------------------------------------------------------------------------
extern "C" void kernel_launch(void* const* d_in, const int* in_sizes, int n_in,
                              void* d_out, int out_size, void* d_ws, size_t ws_size,
                              hipStream_t stream) {
    const float* x      = (const float*)d_in[0];
    const float* gn_w   = (const float*)d_in[1];
    const float* gn_b   = (const float*)d_in[2];
    const float* qkv_w  = (const float*)d_in[3];
    const float* qkv_b  = (const float*)d_in[4];
    const float* proj_w = (const float*)d_in[5];
    const float* proj_b = (const float*)d_in[6];
    float* out = (float*)d_out;

    char* ws = (char*)d_ws;
    // region0 (33.5 MB) reused over time: hnT -> P_part -> attT
    bf16*  hnT    = (bf16*)ws;
    float* P_part = (float*)ws;                    // 8*32*128*128 fp32 = 16.8 MB
    bf16*  attT   = (bf16*)ws;
    bf16*  qkbuf  = (bf16*)(ws + 33554432);        // [b][1024][4096] bf16 = 67.1 MB
    bf16*  vT     = (bf16*)(ws + 100663296);       // [b][4096][512]  bf16 = 33.5 MB
    bf16*  Pb     = (bf16*)(ws + 134217728);       // 32*128*128 bf16 = 1 MB
    float* stats  = (float*)(ws + 135266304);      // 256*2 fp32
    bf16*  qkv_wb = (bf16*)(ws + 135270400);       // 1536*512 bf16 = 1.5 MB
    bf16*  proj_wb= (bf16*)(ws + 136843264);       // 512*512 bf16 = 0.5 MB

    wconv_kernel<<<768, 256, 0, stream>>>(qkv_w, qkv_wb, 196608);
    wconv_kernel<<<256, 256, 0, stream>>>(proj_w, proj_wb, 65536);
    gn_stats_kernel<<<256, 256, 0, stream>>>(x, stats);
    gn_norm_t_kernel<<<dim3(64, 8, 8), 256, 0, stream>>>(x, gn_w, gn_b, stats, hnT);
    qkv_gemm_kernel<<<dim3(32, 12, 8), 256, 0, stream>>>(hnT, qkv_wb, qkv_b, qkbuf, vT);
    qk_gemm_kernel<<<dim3(8, 32), 256, 0, stream>>>(qkbuf, P_part);
    softmax_kernel<<<4096, 128, 0, stream>>>(P_part, Pb);
    pv_gemm_kernel<<<dim3(32, 32), 256, 0, stream>>>(Pb, vT, attT);
    proj_gemm_kernel<<<dim3(32, 4, 8), 256, 0, stream>>>(attT, proj_wb, proj_b, x, out);
}